// Round 5
// baseline (740.419 us; speedup 1.0000x reference)
//
#include <hip/hip_runtime.h>
#include <hip/hip_cooperative_groups.h>

namespace cg = cooperative_groups;

typedef __attribute__((ext_vector_type(8))) short short8;
typedef __attribute__((ext_vector_type(4))) float f32x4;

__device__ __forceinline__ unsigned short f2bf(float f) {
    unsigned u = __builtin_bit_cast(unsigned, f);
    unsigned r = (u + 0x7FFFu + ((u >> 16) & 1u)) >> 16;
    return (unsigned short)r;
}
__device__ __forceinline__ float bf2f(unsigned short u) {
    unsigned v = ((unsigned)u) << 16;
    return __builtin_bit_cast(float, v);
}

// async global->LDS, 16B per lane; LDS dest = wave-uniform base + lane*16
__device__ __forceinline__ void gload16(const unsigned short* g, unsigned short* l) {
    __builtin_amdgcn_global_load_lds(
        (const __attribute__((address_space(1))) void*)g,
        (__attribute__((address_space(3))) void*)l,
        16, 0, 0);
}

#define WAITV(N) asm volatile("s_waitcnt vmcnt(" #N ")" ::: "memory")
#define BAR() do { asm volatile("" ::: "memory"); __builtin_amdgcn_s_barrier(); asm volatile("" ::: "memory"); } while (0)

// ---- one fp32->bf16 chunk (8 elems), chunk id t in [0, 728576) ----
__device__ __forceinline__ void convert_chunk(
    int t,
    const float* __restrict__ x,  const float* __restrict__ w0,
    const float* __restrict__ w1, const float* __restrict__ w2,
    unsigned short* __restrict__ xb,  unsigned short* __restrict__ w0b,
    unsigned short* __restrict__ w1b, unsigned short* __restrict__ w2b)
{
    const int nx  = (1024 * 480) / 8;       // 61440
    const int nw0 = (8 * 512 * 480) / 8;    // 245760
    const int nw1 = (8 * 512 * 512) / 8;    // 262144
    const float* src; unsigned short* dst;
    if (t < nx)                { src = x;  dst = xb;  }
    else if ((t -= nx)  < nw0) { src = w0; dst = w0b; }
    else if ((t -= nw0) < nw1) { src = w1; dst = w1b; }
    else { t -= nw1;             src = w2; dst = w2b; }
    const float4* s4 = (const float4*)src;
    float4 a = s4[2 * t], b = s4[2 * t + 1];
    union { unsigned short u[8]; int4 v; } r;
    r.u[0] = f2bf(a.x); r.u[1] = f2bf(a.y); r.u[2] = f2bf(a.z); r.u[3] = f2bf(a.w);
    r.u[4] = f2bf(b.x); r.u[5] = f2bf(b.y); r.u[6] = f2bf(b.z); r.u[7] = f2bf(b.w);
    ((int4*)dst)[t] = r.v;
}

// ---- batched per-expert NT GEMM stage with fused blend+bias epilogue ----
// Identical structure to the validated round-4 kernel; nxt = # of 128-col tiles.
__device__ __forceinline__ void gemm_stage(
    const unsigned short* __restrict__ A,
    const unsigned short* __restrict__ W,
    const float* __restrict__ blend,   // [E][1024]
    const float* __restrict__ bias,    // [E][N]
    unsigned short* __restrict__ Y,
    int K, int N, int ldy, int nxt,
    unsigned short (&As)[3][128][32], unsigned short (&Bs)[3][128][32])
{
    const int bid = blockIdx.x;
    if (bid >= 64 * nxt) return;                  // inactive block (layer 2: 192 of 256)
    const int e   = bid / (8 * nxt);
    const int rem = bid - e * 8 * nxt;
    const int bm  = (rem / nxt) * 128;
    const int on  = (rem % nxt) * 128;

    const int t    = threadIdx.x;
    const int lane = t & 63;
    const int w    = t >> 6;        // 0..7
    const int wr   = w >> 2;        // 0..1  (64-row band)
    const int wc   = w & 3;         // 0..3  (32-col band)

    const unsigned short* Wt = W + (size_t)e * N * K;

    const int sr = lane >> 2;
    const int sc = (lane & 3) * 8;
    const int ra = w * 16 + sr;
    int rb = on + ra; if (rb > N - 1) rb = N - 1;
    const unsigned short* gA = A  + (size_t)(bm + ra) * K + sc;
    const unsigned short* gB = Wt + (size_t)rb * K + sc;

    const int ktn = K / 32;

#define STAGE(buf, kt) do { int _k0 = (kt) * 32;                       \
        gload16(gA + _k0, &As[(buf)][w * 16][0]);                      \
        gload16(gB + _k0, &Bs[(buf)][w * 16][0]); } while (0)

    f32x4 acc[4][2] = {};

    STAGE(0, 0); STAGE(1, 1); STAGE(2, 2);

    int cur = 0;
    for (int kt = 0; kt < ktn; ++kt) {
        int ahead = ktn - 1 - kt;
        if (ahead >= 2)      WAITV(4);
        else if (ahead == 1) WAITV(2);
        else                 WAITV(0);
        BAR();

        short8 af[4], bfr[2];
        #pragma unroll
        for (int fm = 0; fm < 4; ++fm)
            af[fm] = *(const short8*)&As[cur][wr * 64 + fm * 16 + (lane & 15)][(lane >> 4) * 8];
        #pragma unroll
        for (int fn = 0; fn < 2; ++fn)
            bfr[fn] = *(const short8*)&Bs[cur][wc * 32 + fn * 16 + (lane & 15)][(lane >> 4) * 8];
        #pragma unroll
        for (int fm = 0; fm < 4; ++fm)
            #pragma unroll
            for (int fn = 0; fn < 2; ++fn)
                acc[fm][fn] = __builtin_amdgcn_mfma_f32_16x16x32_bf16(
                    af[fm], bfr[fn], acc[fm][fn], 0, 0, 0);

        BAR();
        if (kt + 3 < ktn) STAGE(cur, kt + 3);
        cur = (cur == 2) ? 0 : cur + 1;
    }
#undef STAGE

    const float* blendE = blend + e * 1024;
    const float* biasE  = bias + (size_t)e * N;
    unsigned short* Ye  = Y + (size_t)e * 1024 * ldy;
    #pragma unroll
    for (int fm = 0; fm < 4; ++fm) {
        int i0 = bm + wr * 64 + fm * 16 + (lane >> 4) * 4;
        float4 bl = *(const float4*)&blendE[i0];
        #pragma unroll
        for (int fn = 0; fn < 2; ++fn) {
            int j = on + wc * 32 + fn * 16 + (lane & 15);
            if (j < N) {
                float bs = biasE[j];
                #pragma unroll
                for (int r = 0; r < 4; ++r)
                    Ye[(size_t)(i0 + r) * ldy + j] = f2bf((acc[fm][fn][r] + bs) * ((&bl.x)[r]));
            }
        }
    }
}

// ---- sum 8 bf16 partial planes + ELU -> bf16 (N=512 layers) ----
__device__ __forceinline__ void reduce8_stage(
    const unsigned short* __restrict__ Y,  // [8][1024][512]
    unsigned short* __restrict__ out)      // [1024][512]
{
    int idx = blockIdx.x * 512 + threadIdx.x;
    if (idx >= 65536) return;
    int b  = idx >> 6;
    int o0 = (idx & 63) * 8;
    size_t base = (size_t)b * 512 + o0;
    float s[8] = {};
    #pragma unroll
    for (int e = 0; e < 8; ++e) {
        int4 v = *(const int4*)&Y[base + (size_t)e * 1024 * 512];
        const unsigned short* u = (const unsigned short*)&v;
        #pragma unroll
        for (int r = 0; r < 8; ++r) s[r] += bf2f(u[r]);
    }
    union { unsigned short u[8]; int4 v; } rr;
    #pragma unroll
    for (int r = 0; r < 8; ++r) {
        float v = (s[r] > 0.f) ? s[r] : expm1f(s[r]);
        rr.u[r] = f2bf(v);
    }
    *(int4*)&out[base] = rr.v;
}

// ---- final reduce: N=311 (planes ldy=320), fp32 out, no activation ----
__device__ __forceinline__ void reduce_last_stage(
    const unsigned short* __restrict__ Y,  // [8][1024][320]
    float* __restrict__ out)               // [1024][311]
{
    int idx = blockIdx.x * 512 + threadIdx.x;
    if (idx >= 1024 * 40) return;
    int b  = idx / 40;
    int o0 = (idx - b * 40) * 8;
    size_t base = (size_t)b * 320 + o0;
    float s[8] = {};
    #pragma unroll
    for (int e = 0; e < 8; ++e) {
        int4 v = *(const int4*)&Y[base + (size_t)e * 1024 * 320];
        const unsigned short* u = (const unsigned short*)&v;
        #pragma unroll
        for (int r = 0; r < 8; ++r) s[r] += bf2f(u[r]);
    }
    #pragma unroll
    for (int r = 0; r < 8; ++r)
        if (o0 + r < 311) out[(size_t)b * 311 + o0 + r] = s[r];
}

// ================= cooperative mega-kernel: all 7 stages =================
__global__ __launch_bounds__(512) void mega(
    const float* __restrict__ x,  const float* __restrict__ blend,
    const float* __restrict__ w0, const float* __restrict__ b0,
    const float* __restrict__ w1, const float* __restrict__ b1,
    const float* __restrict__ w2, const float* __restrict__ b2,
    float* __restrict__ out, char* __restrict__ ws)
{
    __shared__ unsigned short As[3][128][32];
    __shared__ unsigned short Bs[3][128][32];
    cg::grid_group grid = cg::this_grid();

    unsigned short* xb  = (unsigned short*)(ws + 0);
    unsigned short* w0b = (unsigned short*)(ws + 983040);
    unsigned short* w1b = (unsigned short*)(ws + 4915200);
    unsigned short* w2b = (unsigned short*)(ws + 9109504);
    unsigned short* h1b = (unsigned short*)(ws + 11657216);
    unsigned short* h2b = (unsigned short*)(ws + 12705792);
    unsigned short* yb  = (unsigned short*)(ws + 13754368);

#define GSYNC() do { __threadfence(); grid.sync(); __threadfence(); } while (0)

    // S0: convert fp32 -> bf16 (x, w0, w1, w2); 728576 chunks, grid-stride
    {
        int gid = blockIdx.x * 512 + threadIdx.x;
        for (int t = gid; t < 728576; t += 131072)
            convert_chunk(t, x, w0, w1, w2, xb, w0b, w1b, w2b);
    }
    GSYNC();

    // layer 0: K=480, N=512
    gemm_stage(xb, w0b, blend, b0, yb, 480, 512, 512, 4, As, Bs);
    GSYNC();
    reduce8_stage(yb, h1b);
    GSYNC();

    // layer 1: K=512, N=512
    gemm_stage(h1b, w1b, blend, b1, yb, 512, 512, 512, 4, As, Bs);
    GSYNC();
    reduce8_stage(yb, h2b);
    GSYNC();

    // layer 2: K=512, N=311 (ldy=320)
    gemm_stage(h2b, w2b, blend, b2, yb, 512, 311, 320, 3, As, Bs);
    GSYNC();
    reduce_last_stage(yb, out);
#undef GSYNC
}

extern "C" void kernel_launch(void* const* d_in, const int* in_sizes, int n_in,
                              void* d_out, int out_size, void* d_ws, size_t ws_size,
                              hipStream_t stream) {
    const float* x     = (const float*)d_in[0];
    const float* blend = (const float*)d_in[1];
    const float* w0    = (const float*)d_in[2];
    const float* b0    = (const float*)d_in[3];
    const float* w1    = (const float*)d_in[4];
    const float* b1    = (const float*)d_in[5];
    const float* w2    = (const float*)d_in[6];
    const float* b2    = (const float*)d_in[7];
    float* out = (float*)d_out;
    char* ws   = (char*)d_ws;

    void* args[] = {
        (void*)&x,  (void*)&blend, (void*)&w0, (void*)&b0,
        (void*)&w1, (void*)&b1,    (void*)&w2, (void*)&b2,
        (void*)&out, (void*)&ws
    };
    hipLaunchCooperativeKernel((const void*)mega, dim3(256), dim3(512),
                               args, 0, stream);
}

// Round 6
// 67.919 us; speedup vs baseline: 10.9015x; 10.9015x over previous
//
#include <hip/hip_runtime.h>

typedef __attribute__((ext_vector_type(8))) short short8;
typedef __attribute__((ext_vector_type(4))) float f32x4;

__device__ __forceinline__ unsigned short f2bf(float f) {
    unsigned u = __builtin_bit_cast(unsigned, f);
    unsigned r = (u + 0x7FFFu + ((u >> 16) & 1u)) >> 16;
    return (unsigned short)r;
}
__device__ __forceinline__ float bf2f(unsigned short u) {
    unsigned v = ((unsigned)u) << 16;
    return __builtin_bit_cast(float, v);
}

// async global->LDS, 16B per lane; LDS dest = wave-uniform base + lane*16
__device__ __forceinline__ void gload16(const unsigned short* g, unsigned short* l) {
    __builtin_amdgcn_global_load_lds(
        (const __attribute__((address_space(1))) void*)g,
        (__attribute__((address_space(3))) void*)l,
        16, 0, 0);
}

#define WAITV(N) asm volatile("s_waitcnt vmcnt(" #N ")" ::: "memory")
#define BAR() do { asm volatile("" ::: "memory"); __builtin_amdgcn_s_barrier(); asm volatile("" ::: "memory"); } while (0)

// ---- fused fp32 -> bf16 conversion: x, w0, w1, w2 (8 elems/thread) ----
__global__ __launch_bounds__(256) void k_convert(
    const float* __restrict__ x,  const float* __restrict__ w0,
    const float* __restrict__ w1, const float* __restrict__ w2,
    unsigned short* __restrict__ xb,  unsigned short* __restrict__ w0b,
    unsigned short* __restrict__ w1b, unsigned short* __restrict__ w2b)
{
    const int nx  = (1024 * 480) / 8;
    const int nw0 = (8 * 512 * 480) / 8;
    const int nw1 = (8 * 512 * 512) / 8;
    const int nw2 = (8 * 311 * 512) / 8;
    int t = blockIdx.x * 256 + threadIdx.x;
    const float* src; unsigned short* dst;
    if (t < nx)                { src = x;  dst = xb;  }
    else if ((t -= nx)  < nw0) { src = w0; dst = w0b; }
    else if ((t -= nw0) < nw1) { src = w1; dst = w1b; }
    else if ((t -= nw1) < nw2) { src = w2; dst = w2b; }
    else return;
    const float4* s4 = (const float4*)src;
    float4 a = s4[2 * t], b = s4[2 * t + 1];
    union { unsigned short u[8]; int4 v; } r;
    r.u[0] = f2bf(a.x); r.u[1] = f2bf(a.y); r.u[2] = f2bf(a.z); r.u[3] = f2bf(a.w);
    r.u[4] = f2bf(b.x); r.u[5] = f2bf(b.y); r.u[6] = f2bf(b.z); r.u[7] = f2bf(b.w);
    ((int4*)dst)[t] = r.v;
}

// ---- batched per-expert NT GEMM, split-K x2, fused blend(+bias) epilogue ----
// A: [1024][K] bf16; W: [E][N][K] bf16
// Y plane p = e*2+kh: [16][1024][ldy] bf16 = blend_e * (A*W_e^T over K-half + bias_e*[kh==0])
// 128x128 tile, 8 waves (2x4 of 64x32), BK=32, depth-3 pipelined glds staging.
// blockIdx.z = e*2+kh -> grid 512 blocks = 2 blocks/CU = 4 waves/SIMD.
__global__ __launch_bounds__(512) void k_gemm(
    const unsigned short* __restrict__ A,
    const unsigned short* __restrict__ W,
    const float* __restrict__ blend,   // [E][1024]
    const float* __restrict__ bias,    // [E][N]
    unsigned short* __restrict__ Y,
    int K, int N, int ldy)
{
    __shared__ unsigned short As[3][128][32];  // 24 KB
    __shared__ unsigned short Bs[3][128][32];  // 24 KB

    const int z  = blockIdx.z;      // 0..15
    const int e  = z >> 1;
    const int kh = z & 1;
    const int bm = blockIdx.y * 128;
    const int on = blockIdx.x * 128;
    const int t  = threadIdx.x;
    const int lane = t & 63;
    const int w  = t >> 6;          // 0..7
    const int wr = w >> 2;          // 0..1  (64-row band)
    const int wc = w & 3;           // 0..3  (32-col band)

    const unsigned short* Wt = W + (size_t)e * N * K;

    const int sr = lane >> 2;
    const int sc = (lane & 3) * 8;
    const int ra = w * 16 + sr;
    int rb = on + ra; if (rb > N - 1) rb = N - 1;     // clamp for N=311 tail tile
    const unsigned short* gA = A  + (size_t)(bm + ra) * K + sc;
    const unsigned short* gB = Wt + (size_t)rb * K + sc;

    // K-split: kh==0 -> kt [0,8), kh==1 -> kt [8, K/32)
    const int ktn_all = K / 32;                 // 15 or 16
    const int kt0     = kh * 8;
    const int ktn     = (kh == 0) ? 8 : (ktn_all - 8);   // 8 or 7/8

#define STAGE(buf, kt) do { int _k0 = (kt0 + (kt)) * 32;               \
        gload16(gA + _k0, &As[(buf)][w * 16][0]);                      \
        gload16(gB + _k0, &Bs[(buf)][w * 16][0]); } while (0)

    f32x4 acc[4][2] = {};

    STAGE(0, 0); STAGE(1, 1); STAGE(2, 2);   // 6 loads in flight / thread

    int cur = 0;
    for (int kt = 0; kt < ktn; ++kt) {
        int ahead = ktn - 1 - kt;
        if (ahead >= 2)      WAITV(4);
        else if (ahead == 1) WAITV(2);
        else                 WAITV(0);
        BAR();

        short8 af[4], bfr[2];
        #pragma unroll
        for (int fm = 0; fm < 4; ++fm)
            af[fm] = *(const short8*)&As[cur][wr * 64 + fm * 16 + (lane & 15)][(lane >> 4) * 8];
        #pragma unroll
        for (int fn = 0; fn < 2; ++fn)
            bfr[fn] = *(const short8*)&Bs[cur][wc * 32 + fn * 16 + (lane & 15)][(lane >> 4) * 8];
        #pragma unroll
        for (int fm = 0; fm < 4; ++fm)
            #pragma unroll
            for (int fn = 0; fn < 2; ++fn)
                acc[fm][fn] = __builtin_amdgcn_mfma_f32_16x16x32_bf16(
                    af[fm], bfr[fn], acc[fm][fn], 0, 0, 0);

        BAR();
        if (kt + 3 < ktn) STAGE(cur, kt + 3);
        cur = (cur == 2) ? 0 : cur + 1;
    }
#undef STAGE

    // epilogue: D j = lane&15, i = 4*(lane>>4)+r
    // plane z: y = (acc + bias_e[j]*[kh==0]) * blend_e[i]
    const float* blendE = blend + e * 1024;
    const float* biasE  = bias + (size_t)e * N;
    unsigned short* Ye  = Y + (size_t)z * 1024 * ldy;
    #pragma unroll
    for (int fm = 0; fm < 4; ++fm) {
        int i0 = bm + wr * 64 + fm * 16 + (lane >> 4) * 4;
        float4 bl = *(const float4*)&blendE[i0];
        #pragma unroll
        for (int fn = 0; fn < 2; ++fn) {
            int j = on + wc * 32 + fn * 16 + (lane & 15);
            if (j < N) {
                float bs = (kh == 0) ? biasE[j] : 0.f;
                #pragma unroll
                for (int r = 0; r < 4; ++r)
                    Ye[(size_t)(i0 + r) * ldy + j] = f2bf((acc[fm][fn][r] + bs) * ((&bl.x)[r]));
            }
        }
    }
}

// ---- sum 16 bf16 partial planes + ELU, 8 outputs/thread, bf16 out (N=512) ----
__global__ __launch_bounds__(256) void k_reduce16(
    const unsigned short* __restrict__ Y,  // [16][1024][512] bf16
    unsigned short* __restrict__ out)      // [1024][512] bf16
{
    int idx = blockIdx.x * 256 + threadIdx.x;     // 65536 threads
    int b  = idx >> 6;
    int o0 = (idx & 63) * 8;
    size_t base = (size_t)b * 512 + o0;
    float s[8] = {};
    #pragma unroll
    for (int p = 0; p < 16; ++p) {
        int4 v = *(const int4*)&Y[base + (size_t)p * 1024 * 512];
        const unsigned short* u = (const unsigned short*)&v;
        #pragma unroll
        for (int r = 0; r < 8; ++r) s[r] += bf2f(u[r]);
    }
    union { unsigned short u[8]; int4 v; } rr;
    #pragma unroll
    for (int r = 0; r < 8; ++r) {
        float v = (s[r] > 0.f) ? s[r] : expm1f(s[r]);
        rr.u[r] = f2bf(v);
    }
    *(int4*)&out[base] = rr.v;
}

// ---- final reduce: 16 planes, N=311 (ldy=320), fp32 out, no activation ----
__global__ __launch_bounds__(256) void k_reduce_last(
    const unsigned short* __restrict__ Y,  // [16][1024][320] bf16
    float* __restrict__ out)               // [1024][311] fp32
{
    int idx = blockIdx.x * 256 + threadIdx.x;     // 1024*40 = 40960 threads
    if (idx >= 1024 * 40) return;
    int b  = idx / 40;
    int o0 = (idx - b * 40) * 8;                  // 0..312
    size_t base = (size_t)b * 320 + o0;
    float s[8] = {};
    #pragma unroll
    for (int p = 0; p < 16; ++p) {
        int4 v = *(const int4*)&Y[base + (size_t)p * 1024 * 320];
        const unsigned short* u = (const unsigned short*)&v;
        #pragma unroll
        for (int r = 0; r < 8; ++r) s[r] += bf2f(u[r]);
    }
    #pragma unroll
    for (int r = 0; r < 8; ++r)
        if (o0 + r < 311) out[(size_t)b * 311 + o0 + r] = s[r];
}

extern "C" void kernel_launch(void* const* d_in, const int* in_sizes, int n_in,
                              void* d_out, int out_size, void* d_ws, size_t ws_size,
                              hipStream_t stream) {
    const float* x     = (const float*)d_in[0];
    const float* blend = (const float*)d_in[1];
    const float* w0    = (const float*)d_in[2];
    const float* b0    = (const float*)d_in[3];
    const float* w1    = (const float*)d_in[4];
    const float* b1    = (const float*)d_in[5];
    const float* w2    = (const float*)d_in[6];
    const float* b2    = (const float*)d_in[7];

    char* ws = (char*)d_ws;
    unsigned short* xb  = (unsigned short*)(ws + 0);          //   983,040
    unsigned short* w0b = (unsigned short*)(ws + 983040);     // 3,932,160
    unsigned short* w1b = (unsigned short*)(ws + 4915200);    // 4,194,304
    unsigned short* w2b = (unsigned short*)(ws + 9109504);    // 2,547,712
    unsigned short* h1b = (unsigned short*)(ws + 11657216);   // 1,048,576
    unsigned short* h2b = (unsigned short*)(ws + 12705792);   // 1,048,576
    unsigned short* yb  = (unsigned short*)(ws + 13754368);   // 16,777,216 (16 bf16 planes)
    // total ~30.5 MB

    k_convert<<<2846, 256, 0, stream>>>(x, w0, w1, w2, xb, w0b, w1b, w2b);

    // layer 0: K=480, N=512   (512 blocks = 2/CU)
    k_gemm<<<dim3(4, 8, 16), 512, 0, stream>>>(xb, w0b, blend, b0, yb, 480, 512, 512);
    k_reduce16<<<256, 256, 0, stream>>>(yb, h1b);

    // layer 1: K=512, N=512
    k_gemm<<<dim3(4, 8, 16), 512, 0, stream>>>(h1b, w1b, blend, b1, yb, 512, 512, 512);
    k_reduce16<<<256, 256, 0, stream>>>(yb, h2b);

    // layer 2: K=512, N=311 (ldy=320), no ELU, fp32 out  (384 blocks)
    k_gemm<<<dim3(3, 8, 16), 512, 0, stream>>>(h2b, w2b, blend, b2, yb, 512, 311, 320);
    k_reduce_last<<<160, 256, 0, stream>>>(yb, (float*)d_out);
}